// Round 8
// baseline (1513.858 us; speedup 1.0000x reference)
//
#include <hip/hip_runtime.h>

#define NN 64
#define NI 6
#define TT 1024
#define BB 1024
#define TB (TT * BB)
#define NSCALE 0.13416407864998738f        // sqrt(2/alpha) * sigma
#define ARNSCALE 0.013416407864998739f     // alpha * NSCALE
#define RREC 72                            // rnu_t record: 64 rn + 6 uterm + 2 pad
#define BSTRIDE (TT * RREC)                // 73728 floats per batch

__device__ __forceinline__ float rdlane(float v, int l) {
    return __int_as_float(__builtin_amdgcn_readlane(__float_as_int(v), l));
}

// ---------------- Pass 1: build rnu_t[b][t][72] in d_ws ----------------
// record[0..63]  = rn[n][t][b] transposed (n contiguous)
// record[64..69] = u[i][t][b] + NSCALE*inn[i][t][b];  [70..71] = 0
// grid: 1024 t-planes x 16 b-tiles; block 256 thr. All reads/writes coalesced.
__global__ __launch_bounds__(256) void build_rnu(
    const float* __restrict__ u,
    const float* __restrict__ rn,
    const float* __restrict__ inn,
    float* __restrict__ rnu)
{
    const int blk = blockIdx.x;
    const int t   = blk >> 4;
    const int b0  = (blk & 15) * 64;
    const int tid = threadIdx.x;

    __shared__ float lds[64][65];

    // Phase A: read rn 64n x 64b tile (coalesced along b), store transposed
    {
        const int c = tid & 63;           // b-col
        const int r0 = tid >> 6;          // n-row base
#pragma unroll
        for (int it = 0; it < 16; ++it) {
            const int n = 4 * it + r0;
            lds[c][n] = rn[n * TB + t * BB + b0 + c];
        }
    }
    __syncthreads();
    // Phase B: write 64 b-rows, 64 n's contiguous each (coalesced)
    {
        const int cn = tid & 63;          // n-col
        const int r0 = tid >> 6;          // b-row base
#pragma unroll
        for (int it = 0; it < 16; ++it) {
            const int r = 4 * it + r0;
            rnu[(b0 + r) * BSTRIDE + t * RREC + cn] = lds[r][cn];
        }
    }
    // Phase C: uterm (+ zero pad) — 8 floats per b
    {
        const int i  = tid & 7;
        const int br = tid >> 3;          // 0..31
#pragma unroll
        for (int it = 0; it < 2; ++it) {
            const int b = br + 32 * it;
            float v = 0.0f;
            if (i < NI) {
                const int g = i * TB + t * BB + b0 + b;
                v = fmaf(NSCALE, inn[g], u[g]);
            }
            rnu[(b0 + b) * BSTRIDE + t * RREC + 64 + i] = v;
        }
    }
}

// ---------------- Pass 2: recurrence ----------------
// 1024 blocks x 64 thr; block = batch, lane = neuron. W_rec row in 64 VGPRs
// (round-3 evidence: holds at block=64). Zero LDS, zero barriers. Per step:
// one coalesced 256B rn load + one 1-line uterm load + scatter store.
__global__ __launch_bounds__(64) void latent_rnn3(
    const float* __restrict__ rnu,    // (B, T, 72)
    const float* __restrict__ Winp,   // (64, 6)
    const float* __restrict__ Wrec,   // (64, 64)
    float* __restrict__ states)       // (64, T, B)
{
    // XCD swizzle: 128 consecutive batches per XCD
    const int hw = blockIdx.x;
    const int b  = (hw & 7) * 128 + (hw >> 3);
    const int n  = threadIdx.x;

    float wr[NN];
#pragma unroll
    for (int k = 0; k < NN; k += 4) {
        const float4 w4 = *reinterpret_cast<const float4*>(Wrec + n * NN + k);
        wr[k] = w4.x; wr[k + 1] = w4.y; wr[k + 2] = w4.z; wr[k + 3] = w4.w;
    }
    float wi[NI];
#pragma unroll
    for (int i = 0; i < NI; ++i) wi[i] = Winp[n * NI + i];

    const float* rptr = rnu + b * BSTRIDE + n;            // rn lane view
    const float* uptr = rnu + b * BSTRIDE + 64 + (n & 7); // uterm lane view
    float* sdst = states + n * TB + b;

    sdst[0] = 0.0f;   // x[0] = 0

    // prefetch rings, depth 4, static slots
    float rnb[4], utb[4];
#pragma unroll
    for (int d = 0; d < 4; ++d) {
        rnb[d] = rptr[d * RREC];
        utb[d] = uptr[d * RREC];
    }

    float x = 0.0f;

#define STEP(tcur, slot)                                                      \
    do {                                                                      \
        const float rcur = rnb[slot];                                         \
        const float ucur = utb[slot];                                         \
        { const int tp = ((tcur) + 4 < TT - 2) ? (tcur) + 4 : TT - 2;         \
          rnb[slot] = rptr[tp * RREC];                                        \
          utb[slot] = uptr[tp * RREC]; }                                      \
        float a0 = 0.f, a1 = 0.f, a2 = 0.f, a3 = 0.f;                         \
        _Pragma("unroll")                                                     \
        for (int i = 0; i < NI; i += 2) {                                     \
            a0 = fmaf(rdlane(ucur, i),     wi[i],     a0);                    \
            a1 = fmaf(rdlane(ucur, i + 1), wi[i + 1], a1);                    \
        }                                                                     \
        _Pragma("unroll")                                                     \
        for (int k = 0; k < NN; k += 4) {                                     \
            a0 = fmaf(rdlane(rcur /*dummy-dep-free*/ * 0.0f + rcur, 0) * 0.0f \
                      + rdlane(x, k + 0), wr[k + 0], a0);                     \
            a1 = fmaf(rdlane(x, k + 1), wr[k + 1], a1);                       \
            a2 = fmaf(rdlane(x, k + 2), wr[k + 2], a2);                       \
            a3 = fmaf(rdlane(x, k + 3), wr[k + 3], a3);                       \
        }                                                                     \
        const float pre = (a0 + a1) + (a2 + a3);                              \
        const float act = fmaxf(pre, 0.0f);                                   \
        x = fmaf(0.9f, x, fmaf(0.1f, act, ARNSCALE * rcur));                  \
        sdst[((tcur) + 1) * BB] = x;                                          \
    } while (0)

    // NOTE: the odd expression above is wrong-looking; use the clean form:
#undef STEP
#define STEP(tcur, slot)                                                      \
    do {                                                                      \
        const float rcur = rnb[slot];                                         \
        const float ucur = utb[slot];                                         \
        { const int tp = ((tcur) + 4 < TT - 2) ? (tcur) + 4 : TT - 2;         \
          rnb[slot] = rptr[tp * RREC];                                        \
          utb[slot] = uptr[tp * RREC]; }                                      \
        float a0 = 0.f, a1 = 0.f, a2 = 0.f, a3 = 0.f;                         \
        _Pragma("unroll")                                                     \
        for (int i = 0; i < NI; i += 2) {                                     \
            a0 = fmaf(rdlane(ucur, i),     wi[i],     a0);                    \
            a1 = fmaf(rdlane(ucur, i + 1), wi[i + 1], a1);                    \
        }                                                                     \
        _Pragma("unroll")                                                     \
        for (int k = 0; k < NN; k += 4) {                                     \
            a0 = fmaf(rdlane(x, k + 0), wr[k + 0], a0);                       \
            a1 = fmaf(rdlane(x, k + 1), wr[k + 1], a1);                       \
            a2 = fmaf(rdlane(x, k + 2), wr[k + 2], a2);                       \
            a3 = fmaf(rdlane(x, k + 3), wr[k + 3], a3);                       \
        }                                                                     \
        const float pre = (a0 + a1) + (a2 + a3);                              \
        const float act = fmaxf(pre, 0.0f);                                   \
        x = fmaf(0.9f, x, fmaf(0.1f, act, ARNSCALE * rcur));                  \
        sdst[((tcur) + 1) * BB] = x;                                          \
    } while (0)

#pragma unroll 1
    for (int t = 0; t < 1020; t += 4) {
        STEP(t + 0, 0);
        STEP(t + 1, 1);
        STEP(t + 2, 2);
        STEP(t + 3, 3);
    }
    STEP(1020, 0);
    STEP(1021, 1);
    STEP(1022, 2);
#undef STEP
}

// ---------------- Pass 3: outputs = states @ Wout^T ----------------
__global__ __launch_bounds__(256) void out_proj(
    const float* __restrict__ states,
    const float* __restrict__ Wout,
    float* __restrict__ outputs)
{
    const int g4 = (blockIdx.x * 256 + threadIdx.x) * 4;
    float4 a0 = {0.f, 0.f, 0.f, 0.f};
    float4 a1 = {0.f, 0.f, 0.f, 0.f};
#pragma unroll
    for (int k = 0; k < NN; ++k) {
        const float4 s = *reinterpret_cast<const float4*>(states + k * TB + g4);
        const float w0 = Wout[k];
        const float w1 = Wout[NN + k];
        a0.x = fmaf(s.x, w0, a0.x); a0.y = fmaf(s.y, w0, a0.y);
        a0.z = fmaf(s.z, w0, a0.z); a0.w = fmaf(s.w, w0, a0.w);
        a1.x = fmaf(s.x, w1, a1.x); a1.y = fmaf(s.y, w1, a1.y);
        a1.z = fmaf(s.z, w1, a1.z); a1.w = fmaf(s.w, w1, a1.w);
    }
    *reinterpret_cast<float4*>(outputs + g4)      = a0;
    *reinterpret_cast<float4*>(outputs + TB + g4) = a1;
}

// ---------------- Fallback (round-7 path) if ws is too small ----------------
#define BARRIER() do {                                                        \
    __builtin_amdgcn_sched_barrier(0);                                        \
    asm volatile("s_waitcnt lgkmcnt(0)\n\ts_barrier" ::: "memory");           \
    __builtin_amdgcn_sched_barrier(0);                                        \
} while (0)

__global__ __launch_bounds__(256, 1) void latent_rnn_fb(
    const float* __restrict__ u, const float* __restrict__ rn,
    const float* __restrict__ inn, const float* __restrict__ Winp,
    const float* __restrict__ Wrec, float* __restrict__ states)
{
    const int hw  = blockIdx.x;
    const int lb  = (hw & 7) * 32 + (hw >> 3);
    const int b0  = lb * 4;
    const int tid = threadIdx.x;
    const int l   = tid & 63;
    const int w   = tid >> 6;
    const int n   = tid >> 2;
    const int bs  = tid & 3;

    __shared__ float rnT[2][NN][5];
    __shared__ float xT[2][NN][5];
    __shared__ float iT[2][4][8];

    float wreg[NN];
#pragma unroll
    for (int k = 0; k < NN; k += 4) {
        const float4 w4 = *reinterpret_cast<const float4*>(Wrec + l * NN + k);
        wreg[k] = w4.x; wreg[k+1] = w4.y; wreg[k+2] = w4.z; wreg[k+3] = w4.w;
    }
    float wi[NI];
#pragma unroll
    for (int i = 0; i < NI; ++i) wi[i] = Winp[l * NI + i];

    const float* rsrc = rn + n * TB + b0 + bs;
    float*       sdst = states + n * TB + b0 + bs;
    const bool  ist  = (tid < NI * 4);
    const int   ii   = tid >> 2;
    const int   ib   = tid & 3;
    const float* usrc = u   + ii * TB + b0 + ib;
    const float* isrc = inn + ii * TB + b0 + ib;

    rnT[0][n][bs] = rsrc[0];
    if (ist) iT[0][ib][ii] = fmaf(NSCALE, isrc[0], usrc[0]);
    xT[0][l][w] = 0.0f;

    float rnPF[4], uPF[4], iPF[4];
#pragma unroll
    for (int d = 0; d < 4; ++d) {
        rnPF[d] = rsrc[(d + 1) * BB];
        if (ist) { uPF[d] = usrc[(d + 1) * BB]; iPF[d] = isrc[(d + 1) * BB]; }
    }
    __syncthreads();

    float xreg = 0.0f;

#define FSTEP(tcur, slot, CC)                                                 \
  {                                                                           \
    sdst[(tcur) * BB] = xT[CC][n][bs];                                        \
    const float rcur = rnT[CC][l][w];                                         \
    const float4 iv0 = *reinterpret_cast<const float4*>(&iT[CC][w][0]);       \
    const float2 iv1 = *reinterpret_cast<const float2*>(&iT[CC][w][4]);       \
    float a0 = 0.f, a1 = 0.f, a2 = 0.f, a3 = 0.f;                             \
    _Pragma("unroll")                                                         \
    for (int k = 0; k < NN; k += 4) {                                         \
        a0 = fmaf(rdlane(xreg, k + 0), wreg[k + 0], a0);                      \
        a1 = fmaf(rdlane(xreg, k + 1), wreg[k + 1], a1);                      \
        a2 = fmaf(rdlane(xreg, k + 2), wreg[k + 2], a2);                      \
        a3 = fmaf(rdlane(xreg, k + 3), wreg[k + 3], a3);                      \
    }                                                                         \
    a0 = fmaf(iv0.x, wi[0], a0); a1 = fmaf(iv0.y, wi[1], a1);                 \
    a2 = fmaf(iv0.z, wi[2], a2); a3 = fmaf(iv0.w, wi[3], a3);                 \
    a0 = fmaf(iv1.x, wi[4], a0); a1 = fmaf(iv1.y, wi[5], a1);                 \
    const float pre = (a0 + a1) + (a2 + a3);                                  \
    const float xn  = fmaf(0.9f, xreg,                                        \
                           fmaf(0.1f, fmaxf(pre, 0.f), ARNSCALE * rcur));     \
    xreg = xn;                                                                \
    xT[(CC) ^ 1][l][w] = xn;                                                  \
    rnT[(CC) ^ 1][n][bs] = rnPF[slot];                                        \
    if (ist) iT[(CC) ^ 1][ib][ii] = fmaf(NSCALE, iPF[slot], uPF[slot]);       \
    { int tp = (tcur) + 5; if (tp > TT - 2) tp = TT - 2;                      \
      rnPF[slot] = rsrc[tp * BB];                                             \
      if (ist) { uPF[slot] = usrc[tp * BB]; iPF[slot] = isrc[tp * BB]; } }    \
    BARRIER();                                                                \
  }

#pragma unroll 1
    for (int t = 0; t < 1020; t += 4) {
        FSTEP(t + 0, 0, 0);
        FSTEP(t + 1, 1, 1);
        FSTEP(t + 2, 2, 0);
        FSTEP(t + 3, 3, 1);
    }
    FSTEP(1020, 0, 0);
    FSTEP(1021, 1, 1);
    FSTEP(1022, 2, 0);
#undef FSTEP

    sdst[(TT - 1) * BB] = xT[1][n][bs];
}

extern "C" void kernel_launch(void* const* d_in, const int* in_sizes, int n_in,
                              void* d_out, int out_size, void* d_ws, size_t ws_size,
                              hipStream_t stream) {
    const float* u    = (const float*)d_in[0];
    const float* rn   = (const float*)d_in[1];
    const float* inn  = (const float*)d_in[2];
    const float* Winp = (const float*)d_in[3];
    const float* Wrec = (const float*)d_in[4];
    const float* Wout = (const float*)d_in[5];

    float* states  = (float*)d_out;                          // 64*1024*1024
    float* outputs = (float*)d_out + (size_t)NN * TT * BB;   // 2*1024*1024

    const size_t need = (size_t)BB * TT * RREC * sizeof(float);  // ~302 MB
    if (ws_size >= need) {
        float* rnu = (float*)d_ws;
        build_rnu<<<TT * 16, 256, 0, stream>>>(u, rn, inn, rnu);
        latent_rnn3<<<1024, 64, 0, stream>>>(rnu, Winp, Wrec, states);
    } else {
        latent_rnn_fb<<<256, 256, 0, stream>>>(u, rn, inn, Winp, Wrec, states);
    }
    out_proj<<<1024, 256, 0, stream>>>(states, Wout, outputs);
}

// Round 9
// 766.790 us; speedup vs baseline: 1.9743x; 1.9743x over previous
//
#include <hip/hip_runtime.h>

#define NN 64
#define NI 6
#define TT 1024
#define BB 1024
#define TB (TT * BB)
#define NSCALE 0.13416407864998738f        // sqrt(2/alpha) * sigma
#define ARNSCALE 0.013416407864998739f     // alpha * NSCALE
#define RREC 72                            // rnu record: 64 rn (-> x) + 6 uterm + 2 pad
#define BSTRIDE (TT * RREC)                // 73728 floats per batch

__device__ __forceinline__ float rdlane(float v, int l) {
    return __int_as_float(__builtin_amdgcn_readlane(__float_as_int(v), l));
}

// ---------------- Pass 1: build rnu[b][t][72] in d_ws ----------------
// record[0..63]  = rn[n][t][b] transposed (n contiguous)
// record[64..69] = u[i][t][b] + NSCALE*inn[i][t][b];  [70..71] = 0
__global__ __launch_bounds__(256) void build_rnu(
    const float* __restrict__ u,
    const float* __restrict__ rn,
    const float* __restrict__ inn,
    float* __restrict__ rnu)
{
    const int blk = blockIdx.x;
    const int t   = blk >> 4;
    const int b0  = (blk & 15) * 64;
    const int tid = threadIdx.x;

    __shared__ float lds[64][65];

    {   // read rn 64n x 64b tile (coalesced along b), store transposed
        const int c  = tid & 63;
        const int r0 = tid >> 6;
#pragma unroll
        for (int it = 0; it < 16; ++it) {
            const int n = 4 * it + r0;
            lds[c][n] = rn[n * TB + t * BB + b0 + c];
        }
    }
    __syncthreads();
    {   // write 64 b-rows, 64 n contiguous each (coalesced)
        const int cn = tid & 63;
        const int r0 = tid >> 6;
#pragma unroll
        for (int it = 0; it < 16; ++it) {
            const int r = 4 * it + r0;
            rnu[(b0 + r) * BSTRIDE + t * RREC + cn] = lds[r][cn];
        }
    }
    {   // uterm (+ zero pad) — 8 floats per b
        const int i  = tid & 7;
        const int br = tid >> 3;
#pragma unroll
        for (int it = 0; it < 2; ++it) {
            const int b = br + 32 * it;
            float v = 0.0f;
            if (i < NI) {
                const int g = i * TB + t * BB + b0 + b;
                v = fmaf(NSCALE, inn[g], u[g]);
            }
            rnu[(b0 + b) * BSTRIDE + t * RREC + 64 + i] = v;
        }
    }
}

// ---------------- Pass 2: recurrence (all-coalesced, no scatter) ----------------
// 1024 blocks x 64 thr; block = batch, lane = neuron. W_rec row in 64 VGPRs
// (proven at block=64: VGPR_Count=120). Per step: 256B rn load + 32B uterm load,
// then x[t+1] stored back into record[t][0..63] (consumed; 256B coalesced).
__global__ __launch_bounds__(64) void latent_rnn3b(
    float* __restrict__ rnu,          // (B, T, 72) — read rn/uterm, write x in place
    const float* __restrict__ Winp,   // (64, 6)
    const float* __restrict__ Wrec)   // (64, 64)
{
    const int hw = blockIdx.x;
    const int b  = (hw & 7) * 128 + (hw >> 3);   // XCD swizzle
    const int n  = threadIdx.x;

    float wr[NN];
#pragma unroll
    for (int k = 0; k < NN; k += 4) {
        const float4 w4 = *reinterpret_cast<const float4*>(Wrec + n * NN + k);
        wr[k] = w4.x; wr[k + 1] = w4.y; wr[k + 2] = w4.z; wr[k + 3] = w4.w;
    }
    float wi[NI];
#pragma unroll
    for (int i = 0; i < NI; ++i) wi[i] = Winp[n * NI + i];

    float* base = rnu + b * BSTRIDE;
    const float* rptr = base + n;             // rn lane view
    const float* uptr = base + 64 + (n & 7);  // uterm lane view (lanes 0..5 live)
    float* xdst = base + n;                   // x write-back view

    float rnb[4], utb[4];
#pragma unroll
    for (int d = 0; d < 4; ++d) {
        rnb[d] = rptr[d * RREC];
        utb[d] = uptr[d * RREC];
    }

    float x = 0.0f;

#define STEP(tcur, slot)                                                      \
    do {                                                                      \
        const float rcur = rnb[slot];                                         \
        const float ucur = utb[slot];                                         \
        { const int tp = ((tcur) + 4 < TT - 2) ? (tcur) + 4 : TT - 2;         \
          rnb[slot] = rptr[tp * RREC];                                        \
          utb[slot] = uptr[tp * RREC]; }                                      \
        float a0 = 0.f, a1 = 0.f, a2 = 0.f, a3 = 0.f;                         \
        _Pragma("unroll")                                                     \
        for (int i = 0; i < NI; i += 2) {                                     \
            a0 = fmaf(rdlane(ucur, i),     wi[i],     a0);                    \
            a1 = fmaf(rdlane(ucur, i + 1), wi[i + 1], a1);                    \
        }                                                                     \
        _Pragma("unroll")                                                     \
        for (int k = 0; k < NN; k += 4) {                                     \
            a0 = fmaf(rdlane(x, k + 0), wr[k + 0], a0);                       \
            a1 = fmaf(rdlane(x, k + 1), wr[k + 1], a1);                       \
            a2 = fmaf(rdlane(x, k + 2), wr[k + 2], a2);                       \
            a3 = fmaf(rdlane(x, k + 3), wr[k + 3], a3);                       \
        }                                                                     \
        const float pre = (a0 + a1) + (a2 + a3);                              \
        const float act = fmaxf(pre, 0.0f);                                   \
        x = fmaf(0.9f, x, fmaf(0.1f, act, ARNSCALE * rcur));                  \
        xdst[(tcur) * RREC] = x;   /* record[t] <- x[t+1]; rn[t] consumed */  \
    } while (0)

#pragma unroll 1
    for (int t = 0; t < 1020; t += 4) {
        STEP(t + 0, 0);
        STEP(t + 1, 1);
        STEP(t + 2, 2);
        STEP(t + 3, 3);
    }
    STEP(1020, 0);
    STEP(1021, 1);
    STEP(1022, 2);
#undef STEP
}

// ---------------- Pass 3: transpose + fused output projection ----------------
// states[n][t][b] = (t==0) ? 0 : rnu[b][t-1][n];  outputs = states @ Wout^T.
// 64x65 LDS tile: all global reads/writes coalesced, LDS 2-way banks (free).
__global__ __launch_bounds__(256) void trans_out(
    const float* __restrict__ rnu,
    const float* __restrict__ Wout,     // (2, 64)
    float* __restrict__ states,         // (64, T, B)
    float* __restrict__ outputs)        // (2, T, B)
{
    const int blk = blockIdx.x;
    const int t   = blk >> 4;
    const int b0  = (blk & 15) * 64;
    const int tid = threadIdx.x;

    __shared__ float xt[64][65];   // [b][n]
    __shared__ float wo[2][64];

    if (tid < 128) wo[tid >> 6][tid & 63] = Wout[tid];

    const int col = tid & 63;
    const int r0  = tid >> 6;
    if (t == 0) {
#pragma unroll
        for (int it = 0; it < 16; ++it) xt[4 * it + r0][col] = 0.0f;
    } else {
#pragma unroll
        for (int it = 0; it < 16; ++it) {
            const int r = 4 * it + r0;   // batch within tile
            xt[r][col] = rnu[(b0 + r) * BSTRIDE + (t - 1) * RREC + col];
        }
    }
    __syncthreads();

#pragma unroll
    for (int it = 0; it < 16; ++it) {
        const int n = 4 * it + r0;
        states[n * TB + t * BB + b0 + col] = xt[col][n];
    }

    if (tid < 128) {
        const int o  = tid >> 6;
        const int bb = tid & 63;
        float acc = 0.0f;
#pragma unroll
        for (int k = 0; k < NN; ++k) acc = fmaf(xt[bb][k], wo[o][k], acc);
        outputs[o * TB + t * BB + b0 + bb] = acc;
    }
}

// ---------------- Fallback (no-workspace path, proven correct) ----------------
#define BARRIER() do {                                                        \
    __builtin_amdgcn_sched_barrier(0);                                        \
    asm volatile("s_waitcnt lgkmcnt(0)\n\ts_barrier" ::: "memory");           \
    __builtin_amdgcn_sched_barrier(0);                                        \
} while (0)

__global__ __launch_bounds__(256, 1) void latent_rnn_fb(
    const float* __restrict__ u, const float* __restrict__ rn,
    const float* __restrict__ inn, const float* __restrict__ Winp,
    const float* __restrict__ Wrec, float* __restrict__ states)
{
    const int hw  = blockIdx.x;
    const int lb  = (hw & 7) * 32 + (hw >> 3);
    const int b0  = lb * 4;
    const int tid = threadIdx.x;
    const int l   = tid & 63;
    const int w   = tid >> 6;
    const int n   = tid >> 2;
    const int bs  = tid & 3;

    __shared__ float rnT[2][NN][5];
    __shared__ float xT[2][NN][5];
    __shared__ float iT[2][4][8];

    float wreg[NN];
#pragma unroll
    for (int k = 0; k < NN; k += 4) {
        const float4 w4 = *reinterpret_cast<const float4*>(Wrec + l * NN + k);
        wreg[k] = w4.x; wreg[k+1] = w4.y; wreg[k+2] = w4.z; wreg[k+3] = w4.w;
    }
    float wi[NI];
#pragma unroll
    for (int i = 0; i < NI; ++i) wi[i] = Winp[l * NI + i];

    const float* rsrc = rn + n * TB + b0 + bs;
    float*       sdst = states + n * TB + b0 + bs;
    const bool  ist  = (tid < NI * 4);
    const int   ii   = tid >> 2;
    const int   ib   = tid & 3;
    const float* usrc = u   + ii * TB + b0 + ib;
    const float* isrc = inn + ii * TB + b0 + ib;

    rnT[0][n][bs] = rsrc[0];
    if (ist) iT[0][ib][ii] = fmaf(NSCALE, isrc[0], usrc[0]);
    xT[0][l][w] = 0.0f;

    float rnPF[4], uPF[4], iPF[4];
#pragma unroll
    for (int d = 0; d < 4; ++d) {
        rnPF[d] = rsrc[(d + 1) * BB];
        if (ist) { uPF[d] = usrc[(d + 1) * BB]; iPF[d] = isrc[(d + 1) * BB]; }
    }
    __syncthreads();

    float xreg = 0.0f;

#define FSTEP(tcur, slot, CC)                                                 \
  {                                                                           \
    sdst[(tcur) * BB] = xT[CC][n][bs];                                        \
    const float rcur = rnT[CC][l][w];                                         \
    const float4 iv0 = *reinterpret_cast<const float4*>(&iT[CC][w][0]);       \
    const float2 iv1 = *reinterpret_cast<const float2*>(&iT[CC][w][4]);       \
    float a0 = 0.f, a1 = 0.f, a2 = 0.f, a3 = 0.f;                             \
    _Pragma("unroll")                                                         \
    for (int k = 0; k < NN; k += 4) {                                         \
        a0 = fmaf(rdlane(xreg, k + 0), wreg[k + 0], a0);                      \
        a1 = fmaf(rdlane(xreg, k + 1), wreg[k + 1], a1);                      \
        a2 = fmaf(rdlane(xreg, k + 2), wreg[k + 2], a2);                      \
        a3 = fmaf(rdlane(xreg, k + 3), wreg[k + 3], a3);                      \
    }                                                                         \
    a0 = fmaf(iv0.x, wi[0], a0); a1 = fmaf(iv0.y, wi[1], a1);                 \
    a2 = fmaf(iv0.z, wi[2], a2); a3 = fmaf(iv0.w, wi[3], a3);                 \
    a0 = fmaf(iv1.x, wi[4], a0); a1 = fmaf(iv1.y, wi[5], a1);                 \
    const float pre = (a0 + a1) + (a2 + a3);                                  \
    const float xn  = fmaf(0.9f, xreg,                                        \
                           fmaf(0.1f, fmaxf(pre, 0.f), ARNSCALE * rcur));     \
    xreg = xn;                                                                \
    xT[(CC) ^ 1][l][w] = xn;                                                  \
    rnT[(CC) ^ 1][n][bs] = rnPF[slot];                                        \
    if (ist) iT[(CC) ^ 1][ib][ii] = fmaf(NSCALE, iPF[slot], uPF[slot]);       \
    { int tp = (tcur) + 5; if (tp > TT - 2) tp = TT - 2;                      \
      rnPF[slot] = rsrc[tp * BB];                                             \
      if (ist) { uPF[slot] = usrc[tp * BB]; iPF[slot] = isrc[tp * BB]; } }    \
    BARRIER();                                                                \
  }

#pragma unroll 1
    for (int t = 0; t < 1020; t += 4) {
        FSTEP(t + 0, 0, 0);
        FSTEP(t + 1, 1, 1);
        FSTEP(t + 2, 2, 0);
        FSTEP(t + 3, 3, 1);
    }
    FSTEP(1020, 0, 0);
    FSTEP(1021, 1, 1);
    FSTEP(1022, 2, 0);
#undef FSTEP

    sdst[(TT - 1) * BB] = xT[1][n][bs];
}

__global__ __launch_bounds__(256) void out_proj(
    const float* __restrict__ states,
    const float* __restrict__ Wout,
    float* __restrict__ outputs)
{
    const int g4 = (blockIdx.x * 256 + threadIdx.x) * 4;
    float4 a0 = {0.f, 0.f, 0.f, 0.f};
    float4 a1 = {0.f, 0.f, 0.f, 0.f};
#pragma unroll
    for (int k = 0; k < NN; ++k) {
        const float4 s = *reinterpret_cast<const float4*>(states + k * TB + g4);
        const float w0 = Wout[k];
        const float w1 = Wout[NN + k];
        a0.x = fmaf(s.x, w0, a0.x); a0.y = fmaf(s.y, w0, a0.y);
        a0.z = fmaf(s.z, w0, a0.z); a0.w = fmaf(s.w, w0, a0.w);
        a1.x = fmaf(s.x, w1, a1.x); a1.y = fmaf(s.y, w1, a1.y);
        a1.z = fmaf(s.z, w1, a1.z); a1.w = fmaf(s.w, w1, a1.w);
    }
    *reinterpret_cast<float4*>(outputs + g4)      = a0;
    *reinterpret_cast<float4*>(outputs + TB + g4) = a1;
}

extern "C" void kernel_launch(void* const* d_in, const int* in_sizes, int n_in,
                              void* d_out, int out_size, void* d_ws, size_t ws_size,
                              hipStream_t stream) {
    const float* u    = (const float*)d_in[0];
    const float* rn   = (const float*)d_in[1];
    const float* inn  = (const float*)d_in[2];
    const float* Winp = (const float*)d_in[3];
    const float* Wrec = (const float*)d_in[4];
    const float* Wout = (const float*)d_in[5];

    float* states  = (float*)d_out;                          // 64*1024*1024
    float* outputs = (float*)d_out + (size_t)NN * TT * BB;   // 2*1024*1024

    const size_t need = (size_t)BB * TT * RREC * sizeof(float);  // ~302 MB
    if (ws_size >= need) {
        float* rnu = (float*)d_ws;
        build_rnu<<<TT * 16, 256, 0, stream>>>(u, rn, inn, rnu);
        latent_rnn3b<<<1024, 64, 0, stream>>>(rnu, Winp, Wrec);
        trans_out<<<TT * 16, 256, 0, stream>>>(rnu, Wout, states, outputs);
    } else {
        latent_rnn_fb<<<256, 256, 0, stream>>>(u, rn, inn, Winp, Wrec, states);
        out_proj<<<1024, 256, 0, stream>>>(states, Wout, outputs);
    }
}

// Round 10
// 734.507 us; speedup vs baseline: 2.0611x; 1.0440x over previous
//
#include <hip/hip_runtime.h>

#define NN 64
#define NI 6
#define TT 1024
#define BB 1024
#define TB (TT * BB)
#define NSCALE 0.13416407864998738f        // sqrt(2/alpha) * sigma
#define ARNSCALE 0.013416407864998739f     // alpha * NSCALE
#define RREC 72                            // rnu record: 64 rn' (-> x) + 6 uterm + 2 pad
#define BSTRIDE (TT * RREC)                // 73728 floats per batch

__device__ __forceinline__ float rdlane(float v, int l) {
    return __int_as_float(__builtin_amdgcn_readlane(__float_as_int(v), l));
}

// ---------------- Pass 1: build rnu[b][t][72] in d_ws ----------------
// record[0..63]  = ARNSCALE * rn[n][t][b]   (transposed, n contiguous)
// record[64..69] = u[i][t][b] + NSCALE*inn[i][t][b];  [70..71] = 0
__global__ __launch_bounds__(256) void build_rnu(
    const float* __restrict__ u,
    const float* __restrict__ rn,
    const float* __restrict__ inn,
    float* __restrict__ rnu)
{
    const int blk = blockIdx.x;
    const int t   = blk >> 4;
    const int b0  = (blk & 15) * 64;
    const int tid = threadIdx.x;

    __shared__ float lds[64][65];

    {   // read rn 64n x 64b tile (coalesced along b), store transposed + prescale
        const int c  = tid & 63;
        const int r0 = tid >> 6;
#pragma unroll
        for (int it = 0; it < 16; ++it) {
            const int n = 4 * it + r0;
            lds[c][n] = ARNSCALE * rn[n * TB + t * BB + b0 + c];
        }
    }
    __syncthreads();
    {   // write 64 b-rows, 64 n contiguous each (coalesced)
        const int cn = tid & 63;
        const int r0 = tid >> 6;
#pragma unroll
        for (int it = 0; it < 16; ++it) {
            const int r = 4 * it + r0;
            rnu[(b0 + r) * BSTRIDE + t * RREC + cn] = lds[r][cn];
        }
    }
    {   // uterm (+ zero pad) — 8 floats per b
        const int i  = tid & 7;
        const int br = tid >> 3;
#pragma unroll
        for (int it = 0; it < 2; ++it) {
            const int b = br + 32 * it;
            float v = 0.0f;
            if (i < NI) {
                const int g = i * TB + t * BB + b0 + b;
                v = fmaf(NSCALE, inn[g], u[g]);
            }
            rnu[(b0 + b) * BSTRIDE + t * RREC + 64 + i] = v;
        }
    }
}

// ---------------- Pass 2: recurrence (all-coalesced, no scatter) ----------------
// 1024 blocks x 64 thr; block = batch, lane = neuron; W_rec row in 64 VGPRs.
// rn_in and x_out are the SAME buffer passed as two __restrict__ params: the
// no-alias promise stops the compiler from draining vmcnt(0) between the x
// writeback and the prefetch loads (round-9's 750 cyc/step stall). Safe: record
// t's store happens only after record t's load value was consumed (dep chain),
// and prefetch reads (t+4) are never behind a store to the same address.
__global__ __launch_bounds__(64) void latent_rnn3c(
    const float* __restrict__ rn_in,  // (B, T, 72) — reads
    float* __restrict__ x_out,        // (B, T, 72) — x writeback (same buffer)
    const float* __restrict__ Winp,   // (64, 6)
    const float* __restrict__ Wrec)   // (64, 64)
{
    const int hw = blockIdx.x;
    const int b  = (hw & 7) * 128 + (hw >> 3);   // XCD swizzle
    const int n  = threadIdx.x;

    float wr[NN];
#pragma unroll
    for (int k = 0; k < NN; k += 4) {
        const float4 w4 = *reinterpret_cast<const float4*>(Wrec + n * NN + k);
        wr[k] = w4.x; wr[k + 1] = w4.y; wr[k + 2] = w4.z; wr[k + 3] = w4.w;
    }
    float wi[NI];
#pragma unroll
    for (int i = 0; i < NI; ++i) wi[i] = Winp[n * NI + i];

    const float* rptr = rn_in + b * BSTRIDE + n;             // rn' lane view
    const float* uptr = rn_in + b * BSTRIDE + 64 + (n & 7);  // uterm lane view
    float*       xdst = x_out + b * BSTRIDE + n;             // x writeback view

    float rnb[4], utb[4];
#pragma unroll
    for (int d = 0; d < 4; ++d) {
        rnb[d] = rptr[d * RREC];
        utb[d] = uptr[d * RREC];
    }

    float x = 0.0f;

#define STEP(tcur, slot)                                                      \
    do {                                                                      \
        const float rcur = rnb[slot];                                         \
        const float ucur = utb[slot];                                         \
        { const int tp = ((tcur) + 4 < TT - 2) ? (tcur) + 4 : TT - 2;         \
          rnb[slot] = rptr[tp * RREC];                                        \
          utb[slot] = uptr[tp * RREC]; }                                      \
        float a0 = 0.f, a1 = 0.f, a2 = 0.f, a3 = 0.f;                         \
        _Pragma("unroll")                                                     \
        for (int i = 0; i < NI; i += 2) {                                     \
            a0 = fmaf(rdlane(ucur, i),     wi[i],     a0);                    \
            a1 = fmaf(rdlane(ucur, i + 1), wi[i + 1], a1);                    \
        }                                                                     \
        _Pragma("unroll")                                                     \
        for (int k = 0; k < NN; k += 4) {                                     \
            a0 = fmaf(rdlane(x, k + 0), wr[k + 0], a0);                       \
            a1 = fmaf(rdlane(x, k + 1), wr[k + 1], a1);                       \
            a2 = fmaf(rdlane(x, k + 2), wr[k + 2], a2);                       \
            a3 = fmaf(rdlane(x, k + 3), wr[k + 3], a3);                       \
        }                                                                     \
        const float pre = (a0 + a1) + (a2 + a3);                              \
        const float act = fmaxf(pre, 0.0f);                                   \
        x = fmaf(0.9f, x, fmaf(0.1f, act, rcur));                             \
        xdst[(tcur) * RREC] = x;   /* record[t] <- x[t+1]; rn[t] consumed */  \
    } while (0)

#pragma unroll 1
    for (int t = 0; t < 1020; t += 4) {
        STEP(t + 0, 0);
        STEP(t + 1, 1);
        STEP(t + 2, 2);
        STEP(t + 3, 3);
    }
    STEP(1020, 0);
    STEP(1021, 1);
    STEP(1022, 2);
#undef STEP
}

// ---------------- Pass 3: transpose + fused output projection ----------------
// states[n][t][b] = (t==0) ? 0 : rnu[b][t-1][n];  outputs = states @ Wout^T.
__global__ __launch_bounds__(256) void trans_out(
    const float* __restrict__ rnu,
    const float* __restrict__ Wout,     // (2, 64)
    float* __restrict__ states,         // (64, T, B)
    float* __restrict__ outputs)        // (2, T, B)
{
    const int blk = blockIdx.x;
    const int t   = blk >> 4;
    const int b0  = (blk & 15) * 64;
    const int tid = threadIdx.x;

    __shared__ float xt[64][65];   // [b][n]
    __shared__ float wo[2][64];

    if (tid < 128) wo[tid >> 6][tid & 63] = Wout[tid];

    const int col = tid & 63;
    const int r0  = tid >> 6;
    if (t == 0) {
#pragma unroll
        for (int it = 0; it < 16; ++it) xt[4 * it + r0][col] = 0.0f;
    } else {
#pragma unroll
        for (int it = 0; it < 16; ++it) {
            const int r = 4 * it + r0;   // batch within tile
            xt[r][col] = rnu[(b0 + r) * BSTRIDE + (t - 1) * RREC + col];
        }
    }
    __syncthreads();

#pragma unroll
    for (int it = 0; it < 16; ++it) {
        const int n = 4 * it + r0;
        states[n * TB + t * BB + b0 + col] = xt[col][n];
    }

    if (tid < 128) {
        const int o  = tid >> 6;
        const int bb = tid & 63;
        float acc = 0.0f;
#pragma unroll
        for (int k = 0; k < NN; ++k) acc = fmaf(xt[bb][k], wo[o][k], acc);
        outputs[o * TB + t * BB + b0 + bb] = acc;
    }
}

// ---------------- Fallback (no-workspace path, proven correct) ----------------
#define BARRIER() do {                                                        \
    __builtin_amdgcn_sched_barrier(0);                                        \
    asm volatile("s_waitcnt lgkmcnt(0)\n\ts_barrier" ::: "memory");           \
    __builtin_amdgcn_sched_barrier(0);                                        \
} while (0)

__global__ __launch_bounds__(256, 1) void latent_rnn_fb(
    const float* __restrict__ u, const float* __restrict__ rn,
    const float* __restrict__ inn, const float* __restrict__ Winp,
    const float* __restrict__ Wrec, float* __restrict__ states)
{
    const int hw  = blockIdx.x;
    const int lb  = (hw & 7) * 32 + (hw >> 3);
    const int b0  = lb * 4;
    const int tid = threadIdx.x;
    const int l   = tid & 63;
    const int w   = tid >> 6;
    const int n   = tid >> 2;
    const int bs  = tid & 3;

    __shared__ float rnT[2][NN][5];
    __shared__ float xT[2][NN][5];
    __shared__ float iT[2][4][8];

    float wreg[NN];
#pragma unroll
    for (int k = 0; k < NN; k += 4) {
        const float4 w4 = *reinterpret_cast<const float4*>(Wrec + l * NN + k);
        wreg[k] = w4.x; wreg[k+1] = w4.y; wreg[k+2] = w4.z; wreg[k+3] = w4.w;
    }
    float wi[NI];
#pragma unroll
    for (int i = 0; i < NI; ++i) wi[i] = Winp[l * NI + i];

    const float* rsrc = rn + n * TB + b0 + bs;
    float*       sdst = states + n * TB + b0 + bs;
    const bool  ist  = (tid < NI * 4);
    const int   ii   = tid >> 2;
    const int   ib   = tid & 3;
    const float* usrc = u   + ii * TB + b0 + ib;
    const float* isrc = inn + ii * TB + b0 + ib;

    rnT[0][n][bs] = rsrc[0];
    if (ist) iT[0][ib][ii] = fmaf(NSCALE, isrc[0], usrc[0]);
    xT[0][l][w] = 0.0f;

    float rnPF[4], uPF[4], iPF[4];
#pragma unroll
    for (int d = 0; d < 4; ++d) {
        rnPF[d] = rsrc[(d + 1) * BB];
        if (ist) { uPF[d] = usrc[(d + 1) * BB]; iPF[d] = isrc[(d + 1) * BB]; }
    }
    __syncthreads();

    float xreg = 0.0f;

#define FSTEP(tcur, slot, CC)                                                 \
  {                                                                           \
    sdst[(tcur) * BB] = xT[CC][n][bs];                                        \
    const float rcur = rnT[CC][l][w];                                         \
    const float4 iv0 = *reinterpret_cast<const float4*>(&iT[CC][w][0]);       \
    const float2 iv1 = *reinterpret_cast<const float2*>(&iT[CC][w][4]);       \
    float a0 = 0.f, a1 = 0.f, a2 = 0.f, a3 = 0.f;                             \
    _Pragma("unroll")                                                         \
    for (int k = 0; k < NN; k += 4) {                                         \
        a0 = fmaf(rdlane(xreg, k + 0), wreg[k + 0], a0);                      \
        a1 = fmaf(rdlane(xreg, k + 1), wreg[k + 1], a1);                      \
        a2 = fmaf(rdlane(xreg, k + 2), wreg[k + 2], a2);                      \
        a3 = fmaf(rdlane(xreg, k + 3), wreg[k + 3], a3);                      \
    }                                                                         \
    a0 = fmaf(iv0.x, wi[0], a0); a1 = fmaf(iv0.y, wi[1], a1);                 \
    a2 = fmaf(iv0.z, wi[2], a2); a3 = fmaf(iv0.w, wi[3], a3);                 \
    a0 = fmaf(iv1.x, wi[4], a0); a1 = fmaf(iv1.y, wi[5], a1);                 \
    const float pre = (a0 + a1) + (a2 + a3);                                  \
    const float xn  = fmaf(0.9f, xreg,                                        \
                           fmaf(0.1f, fmaxf(pre, 0.f), ARNSCALE * rcur));     \
    xreg = xn;                                                                \
    xT[(CC) ^ 1][l][w] = xn;                                                  \
    rnT[(CC) ^ 1][n][bs] = rnPF[slot];                                        \
    if (ist) iT[(CC) ^ 1][ib][ii] = fmaf(NSCALE, iPF[slot], uPF[slot]);       \
    { int tp = (tcur) + 5; if (tp > TT - 2) tp = TT - 2;                      \
      rnPF[slot] = rsrc[tp * BB];                                             \
      if (ist) { uPF[slot] = usrc[tp * BB]; iPF[slot] = isrc[tp * BB]; } }    \
    BARRIER();                                                                \
  }

#pragma unroll 1
    for (int t = 0; t < 1020; t += 4) {
        FSTEP(t + 0, 0, 0);
        FSTEP(t + 1, 1, 1);
        FSTEP(t + 2, 2, 0);
        FSTEP(t + 3, 3, 1);
    }
    FSTEP(1020, 0, 0);
    FSTEP(1021, 1, 1);
    FSTEP(1022, 2, 0);
#undef FSTEP

    sdst[(TT - 1) * BB] = xT[1][n][bs];
}

__global__ __launch_bounds__(256) void out_proj(
    const float* __restrict__ states,
    const float* __restrict__ Wout,
    float* __restrict__ outputs)
{
    const int g4 = (blockIdx.x * 256 + threadIdx.x) * 4;
    float4 a0 = {0.f, 0.f, 0.f, 0.f};
    float4 a1 = {0.f, 0.f, 0.f, 0.f};
#pragma unroll
    for (int k = 0; k < NN; ++k) {
        const float4 s = *reinterpret_cast<const float4*>(states + k * TB + g4);
        const float w0 = Wout[k];
        const float w1 = Wout[NN + k];
        a0.x = fmaf(s.x, w0, a0.x); a0.y = fmaf(s.y, w0, a0.y);
        a0.z = fmaf(s.z, w0, a0.z); a0.w = fmaf(s.w, w0, a0.w);
        a1.x = fmaf(s.x, w1, a1.x); a1.y = fmaf(s.y, w1, a1.y);
        a1.z = fmaf(s.z, w1, a1.z); a1.w = fmaf(s.w, w1, a1.w);
    }
    *reinterpret_cast<float4*>(outputs + g4)      = a0;
    *reinterpret_cast<float4*>(outputs + TB + g4) = a1;
}

extern "C" void kernel_launch(void* const* d_in, const int* in_sizes, int n_in,
                              void* d_out, int out_size, void* d_ws, size_t ws_size,
                              hipStream_t stream) {
    const float* u    = (const float*)d_in[0];
    const float* rn   = (const float*)d_in[1];
    const float* inn  = (const float*)d_in[2];
    const float* Winp = (const float*)d_in[3];
    const float* Wrec = (const float*)d_in[4];
    const float* Wout = (const float*)d_in[5];

    float* states  = (float*)d_out;                          // 64*1024*1024
    float* outputs = (float*)d_out + (size_t)NN * TT * BB;   // 2*1024*1024

    const size_t need = (size_t)BB * TT * RREC * sizeof(float);  // ~302 MB
    if (ws_size >= need) {
        float* rnu = (float*)d_ws;
        build_rnu<<<TT * 16, 256, 0, stream>>>(u, rn, inn, rnu);
        latent_rnn3c<<<1024, 64, 0, stream>>>(rnu, rnu, Winp, Wrec);
        trans_out<<<TT * 16, 256, 0, stream>>>(rnu, Wout, states, outputs);
    } else {
        latent_rnn_fb<<<256, 256, 0, stream>>>(u, rn, inn, Winp, Wrec, states);
        out_proj<<<1024, 256, 0, stream>>>(states, Wout, outputs);
    }
}